// Round 11
// baseline (779.227 us; speedup 1.0000x reference)
//
#include <hip/hip_runtime.h>

typedef _Float16 half8 __attribute__((ext_vector_type(8)));
typedef float f32x4 __attribute__((ext_vector_type(4)));
typedef unsigned long long ull;

// ---- ws layout (byte offsets) ----
#define OFF_WTP   0u          // WtP fp16 gate frags [8w][4g][2n][10ks][512] = 655360
#define OFF_WCP   655360u     // WcP fp16 compress frags [8w][8ks][512] = 65536
#define OFF_BIASG 720896u     // biasG f32 [1024] = 4096
#define OFF_WX    724992u     // Wx f32 [768][64] = 196608
#define OFF_XH    921600u     // xH fp16 [1024][64][64] = 8388608
#define OFF_HCP   9310208u    // hcP fp16 [2h][2par][32j][4096] = 1048576
#define OFF_FLAGS 10358784u   // 64 flags x 64-int pad = 16384

// ---- coherent helpers: relaxed agent-scope only (sc1 -> MALL), no acq/rel --
__device__ __forceinline__ int ldrlx(const int* p) {
    return __hip_atomic_load(p, __ATOMIC_RELAXED, __HIP_MEMORY_SCOPE_AGENT);
}
__device__ __forceinline__ void astrlx(int* p, int v) {
    __hip_atomic_store(p, v, __ATOMIC_RELAXED, __HIP_MEMORY_SCOPE_AGENT);
}
__device__ __forceinline__ ull ald64(const void* p) {
    return __hip_atomic_load((const ull*)p, __ATOMIC_RELAXED, __HIP_MEMORY_SCOPE_AGENT);
}
__device__ __forceinline__ void ast64(void* p, ull v) {
    __hip_atomic_store((ull*)p, v, __ATOMIC_RELAXED, __HIP_MEMORY_SCOPE_AGENT);
}

// ---------------- prep kernels ----------------
__global__ __launch_bounds__(256) void k_build_wx(
    const float* __restrict__ W_ih, const float* __restrict__ We,
    float* __restrict__ Wx)
{
    __shared__ float WeS[128][64];
    const int tid = threadIdx.x;
    #pragma unroll
    for (int q = 0; q < 8; ++q) {
        int p = q*256 + tid;
        int e = p >> 4, k4 = p & 15;
        *(float4*)&WeS[e][k4*4] = *(const float4*)&We[e*64 + k4*4];
    }
    __syncthreads();
    int idx = blockIdx.x*256 + tid;     // 49152 -> 192 blocks
    int r = idx >> 6, k = idx & 63;
    float acc = 0.f;
    #pragma unroll 4
    for (int e = 0; e < 128; ++e) acc = fmaf(W_ih[r*128 + e], WeS[e][k], acc);
    Wx[idx] = acc;
}

// gate frags for full-channel waves: [w][g][n][ks], frag = 64 lanes x 8 halves
__global__ __launch_bounds__(512) void k_prep_wtp(
    const float* __restrict__ Wx, const float* __restrict__ W_hh,
    _Float16* __restrict__ WtP)
{
    int bid = blockIdx.x;               // 640 = 8w*4g*2n*10ks
    int w = bid / 80, rem = bid % 80;
    int g = rem / 20, rem2 = rem % 20;
    int n = rem2 / 10, ks = rem2 % 10;
    int t = threadIdx.x;
    int l = t >> 3, e = t & 7;
    int c = w*32 + n*16 + (l & 15);
    int k = ks*32 + (l >> 4)*8 + e;
    float v;
    if (g == 0)      v = (k < 64) ? Wx[c*64 + k]          : W_hh[c*256 + k - 64];
    else if (g == 1) v = (k < 64) ? Wx[(256+c)*64 + k]    : W_hh[(256+c)*256 + k - 64];
    else if (g == 2) v = (k < 64) ? Wx[(512+c)*64 + k]    : 0.f;
    else             v = (k < 64) ? 0.f                   : W_hh[(512+c)*256 + k - 64];
    WtP[(ull)bid*512 + t] = (_Float16)v;
}

// compress frags: [w][ks]; wave w -> out cols w*16..+15
__global__ __launch_bounds__(512) void k_prep_wcp(
    const float* __restrict__ Wc, _Float16* __restrict__ WcP)
{
    int bid = blockIdx.x;               // 64 = 8w*8ks
    int w = bid >> 3, ks = bid & 7;
    int t = threadIdx.x;
    int l = t >> 3, e = t & 7;
    int oc = w*16 + (l & 15);
    int k = ks*32 + (l >> 4)*8 + e;
    WcP[(ull)bid*512 + t] = (_Float16)Wc[oc*256 + k];
}

__global__ __launch_bounds__(256) void k_prep_bias(
    const float* __restrict__ b_ih, const float* __restrict__ b_hh,
    const float* __restrict__ W_ih, const float* __restrict__ be,
    float* __restrict__ biasG)
{
    int row = blockIdx.x*256 + threadIdx.x;   // 1024
    int g = row >> 8, c = row & 255;
    float v;
    if (g < 3) {
        int r = g*256 + c;
        float bx = b_ih[r];
        #pragma unroll 4
        for (int e = 0; e < 128; ++e) bx = fmaf(W_ih[r*128 + e], be[e], bx);
        v = (g == 0) ? bx + b_hh[c] : (g == 1) ? bx + b_hh[256 + c] : bx;
    } else v = b_hh[512 + c];
    biasG[row] = v;
}

__global__ __launch_bounds__(256) void k_prep_x(
    const float* __restrict__ x, _Float16* __restrict__ xH)
{
    int cell = blockIdx.x;              // 1024
    int i = cell >> 5, j = cell & 31;
    int b = threadIdx.x >> 2, k16 = (threadIdx.x & 3)*16;
    const float* src = &x[((b*32 + i)*32 + j)*64 + k16];
    _Float16* dst = &xH[((ull)cell*64 + b)*64 + k16];
    #pragma unroll
    for (int kk = 0; kk < 16; kk += 4) {
        float4 v = *(const float4*)&src[kk];
        dst[kk+0] = (_Float16)v.x; dst[kk+1] = (_Float16)v.y;
        dst[kk+2] = (_Float16)v.z; dst[kk+3] = (_Float16)v.w;
    }
}

// -------- persistent 2D-GRU: BATCH-split (2 independent pipelines), 1 row/WG,
// full channels, weights streamed from L2, hc handoff 8KB via MALL.
// 64 WGs x 512 thr. WG (i = blk>>1, h = blk&1): row i, batches h*32..+31.
__global__ void __launch_bounds__(512, 2)
k_grid(char* __restrict__ wsb, const float* __restrict__ bcb, float* __restrict__ out)
{
    const _Float16* WtP = (const _Float16*)(wsb + OFF_WTP);
    const _Float16* WcP = (const _Float16*)(wsb + OFF_WCP);
    const float*  biasG = (const float*)(wsb + OFF_BIASG);
    const _Float16* xH  = (const _Float16*)(wsb + OFF_XH);
    _Float16* hcP = (_Float16*)(wsb + OFF_HCP);
    int* flags = (int*)(wsb + OFF_FLAGS);

    __shared__ __align__(16) _Float16 As[32][328];   // [b][k 0..319]; cols 0..255 reused as hnew
    __shared__ __align__(16) _Float16 hcPrev[32][136]; // own hc(i,j-1..j) (persists j->j+1)

    const int blk = blockIdx.x;
    const int i = blk >> 1, h = blk & 1;
    const int tid = threadIdx.x;
    const int w = tid >> 6, l = tid & 63;
    const int l15 = l & 15, lhi = l >> 4;
    const int ko = lhi*8;
    const int b32 = tid >> 4, c16 = tid & 15;        // staging decomposition

    // bias scalars: gate g, n-group n, channel c = w*32 + n*16 + l15
    const int c0 = w*32 + l15, c1 = c0 + 16;
    const float bi00 = biasG[c0],     bi01 = biasG[c1];
    const float bi10 = biasG[256+c0], bi11 = biasG[256+c1];
    const float bi20 = biasG[512+c0], bi21 = biasG[512+c1];
    const float bi30 = biasG[768+c0], bi31 = biasG[768+c1];
    const int oc = w*16 + l15;                        // compress out col
    const float bcv = bcb[oc];
    const _Float16* WtPw = WtP + ((ull)w*80)*512 + (ull)l*8;   // + ((g*2+n)*10+ks)*512
    const _Float16* WcPw = WcP + ((ull)w*8)*512 + (ull)l*8;    // + ks*512

    for (int j = 0; j < 32; ++j) {
        // x prefetch (independent of deps): 4 halfs per thread
        uint2 xv = *(const uint2*)&xH[((ull)(i*32 + j)*64 + (h*32 + b32))*64 + c16*4];
        // ---- single dependency poll: row above, own batch half ----
        if (i > 0)
            while (ldrlx(flags + (blk - 2)*64) <= j) __builtin_amdgcn_s_sleep(2);

        // ---- stage A: x | row-above hc (MALL, 8 halfs/thread) | own prev col (LDS) ----
        *(uint2*)&As[b32][c16*4] = xv;
        if (i > 0) {
            const _Float16* src = hcP + ((ull)((h*2 + ((i-1)&1))*32 + j))*4096 + tid*8;
            ull u0 = ald64(src), u1 = ald64(src + 4);
            *(ull*)&As[b32][64 + c16*8]     = u0;
            *(ull*)&As[b32][64 + c16*8 + 4] = u1;
        } else {
            *(ull*)&As[b32][64 + c16*8]     = 0ull;
            *(ull*)&As[b32][64 + c16*8 + 4] = 0ull;
        }
        if (j > 0) {
            uint4 pv = *(const uint4*)&hcPrev[b32][c16*8];
            *(uint4*)&As[b32][192 + c16*8] = pv;
        } else {
            *(ull*)&As[b32][192 + c16*8]     = 0ull;
            *(ull*)&As[b32][192 + c16*8 + 4] = 0ull;
        }
        __syncthreads();   // S2: A staged

        // ---- gate GEMM: M=32, wave covers 32 ch x 4 gates, K=320, B from L2 ----
        f32x4 a00 = {bi00,bi00,bi00,bi00}, a00b = a00;   // [g][n][m]: g0 n0 m0/m1
        f32x4 a01 = {bi01,bi01,bi01,bi01}, a01b = a01;
        f32x4 a10 = {bi10,bi10,bi10,bi10}, a10b = a10;
        f32x4 a11 = {bi11,bi11,bi11,bi11}, a11b = a11;
        f32x4 a20 = {bi20,bi20,bi20,bi20}, a20b = a20;
        f32x4 a21 = {bi21,bi21,bi21,bi21}, a21b = a21;
        f32x4 a30 = {bi30,bi30,bi30,bi30}, a30b = a30;
        f32x4 a31 = {bi31,bi31,bi31,bi31}, a31b = a31;
        #pragma unroll
        for (int ks = 0; ks < 10; ++ks) {
            half8 av0 = *(const half8*)&As[     l15][ks*32 + ko];
            half8 av1 = *(const half8*)&As[16 + l15][ks*32 + ko];
            half8 B00 = *(const half8*)&WtPw[(ull)((0*2+0)*10 + ks)*512];
            half8 B01 = *(const half8*)&WtPw[(ull)((0*2+1)*10 + ks)*512];
            half8 B10 = *(const half8*)&WtPw[(ull)((1*2+0)*10 + ks)*512];
            half8 B11 = *(const half8*)&WtPw[(ull)((1*2+1)*10 + ks)*512];
            a00  = __builtin_amdgcn_mfma_f32_16x16x32_f16(av0, B00, a00, 0,0,0);
            a00b = __builtin_amdgcn_mfma_f32_16x16x32_f16(av1, B00, a00b, 0,0,0);
            a01  = __builtin_amdgcn_mfma_f32_16x16x32_f16(av0, B01, a01, 0,0,0);
            a01b = __builtin_amdgcn_mfma_f32_16x16x32_f16(av1, B01, a01b, 0,0,0);
            a10  = __builtin_amdgcn_mfma_f32_16x16x32_f16(av0, B10, a10, 0,0,0);
            a10b = __builtin_amdgcn_mfma_f32_16x16x32_f16(av1, B10, a10b, 0,0,0);
            a11  = __builtin_amdgcn_mfma_f32_16x16x32_f16(av0, B11, a11, 0,0,0);
            a11b = __builtin_amdgcn_mfma_f32_16x16x32_f16(av1, B11, a11b, 0,0,0);
            if (ks < 2) {
                half8 B20 = *(const half8*)&WtPw[(ull)((2*2+0)*10 + ks)*512];
                half8 B21 = *(const half8*)&WtPw[(ull)((2*2+1)*10 + ks)*512];
                a20  = __builtin_amdgcn_mfma_f32_16x16x32_f16(av0, B20, a20, 0,0,0);
                a20b = __builtin_amdgcn_mfma_f32_16x16x32_f16(av1, B20, a20b, 0,0,0);
                a21  = __builtin_amdgcn_mfma_f32_16x16x32_f16(av0, B21, a21, 0,0,0);
                a21b = __builtin_amdgcn_mfma_f32_16x16x32_f16(av1, B21, a21b, 0,0,0);
            } else {
                half8 B30 = *(const half8*)&WtPw[(ull)((3*2+0)*10 + ks)*512];
                half8 B31 = *(const half8*)&WtPw[(ull)((3*2+1)*10 + ks)*512];
                a30  = __builtin_amdgcn_mfma_f32_16x16x32_f16(av0, B30, a30, 0,0,0);
                a30b = __builtin_amdgcn_mfma_f32_16x16x32_f16(av1, B30, a30b, 0,0,0);
                a31  = __builtin_amdgcn_mfma_f32_16x16x32_f16(av0, B31, a31, 0,0,0);
                a31b = __builtin_amdgcn_mfma_f32_16x16x32_f16(av1, B31, a31b, 0,0,0);
            }
        }
        // ---- gate nonlinearities (in-lane r,z,xn,hn), blend from staged A ----
        float hn0[2][4], hn1[2][4];   // [m][r] for n=0 / n=1
        #pragma unroll
        for (int m = 0; m < 2; ++m) {
            #pragma unroll
            for (int r = 0; r < 4; ++r) {
                const int row = m*16 + lhi*4 + r;
                f32x4 g0 = m ? a00b : a00, g1 = m ? a10b : a10;
                f32x4 g2 = m ? a20b : a20, g3 = m ? a30b : a30;
                float rg = 1.f/(1.f + __expf(-g0[r]));
                float zg = 1.f/(1.f + __expf(-g1[r]));
                float e2 = __expf(2.f*(g2[r] + rg*g3[r]));
                float ng = 1.f - 2.f/(e2 + 1.f);
                float hv = (c0 < 128) ? (float)As[row][64 + c0]
                                      : (float)As[row][192 + c0 - 128];
                hn0[m][r] = (1.f - zg)*ng + zg*hv;
                f32x4 q0 = m ? a01b : a01, q1 = m ? a11b : a11;
                f32x4 q2 = m ? a21b : a21, q3 = m ? a31b : a31;
                float rg1 = 1.f/(1.f + __expf(-q0[r]));
                float zg1 = 1.f/(1.f + __expf(-q1[r]));
                float e21 = __expf(2.f*(q2[r] + rg1*q3[r]));
                float ng1 = 1.f - 2.f/(e21 + 1.f);
                float hv1 = (c1 < 128) ? (float)As[row][64 + c1]
                                       : (float)As[row][192 + c1 - 128];
                hn1[m][r] = (1.f - zg1)*ng1 + zg1*hv1;
            }
        }
        __syncthreads();   // S3: all A reads (GEMM + blend) done
        #pragma unroll
        for (int m = 0; m < 2; ++m)
            #pragma unroll
            for (int r = 0; r < 4; ++r) {
                As[m*16 + lhi*4 + r][c0] = (_Float16)hn0[m][r];
                As[m*16 + lhi*4 + r][c1] = (_Float16)hn1[m][r];
            }
        __syncthreads();   // S4: hnew complete in LDS
        // ---- compress: hc = hnew @ Wc.T + bc (full K=256, B from L2) ----
        f32x4 cc0 = {bcv,bcv,bcv,bcv}, cc1 = cc0;
        #pragma unroll
        for (int ks = 0; ks < 8; ++ks) {
            half8 av0 = *(const half8*)&As[     l15][ks*32 + ko];
            half8 av1 = *(const half8*)&As[16 + l15][ks*32 + ko];
            half8 WB = *(const half8*)&WcPw[(ull)ks*512];
            cc0 = __builtin_amdgcn_mfma_f32_16x16x32_f16(av0, WB, cc0, 0,0,0);
            cc1 = __builtin_amdgcn_mfma_f32_16x16x32_f16(av1, WB, cc1, 0,0,0);
        }
        #pragma unroll
        for (int r = 0; r < 4; ++r) {
            hcPrev[     lhi*4 + r][oc] = (_Float16)cc0[r];
            hcPrev[16 + lhi*4 + r][oc] = (_Float16)cc1[r];
        }
        if (i == 31 && j == 31) {       // final output in fp32 from accumulators
            #pragma unroll
            for (int r = 0; r < 4; ++r) {
                out[(h*32 +      lhi*4 + r)*128 + oc] = cc0[r];
                out[(h*32 + 16 + lhi*4 + r)*128 + oc] = cc1[r];
            }
        }
        __syncthreads();   // S5: hcPrev complete
        // ---- export hc (8 halfs/thread, dense plane, relaxed sc1 -> MALL) ----
        {
            _Float16* dst = hcP + ((ull)((h*2 + (i&1))*32 + j))*4096 + tid*8;
            ast64(dst,     *(const ull*)&hcPrev[b32][c16*8]);
            ast64(dst + 4, *(const ull*)&hcPrev[b32][c16*8 + 4]);
        }
        __syncthreads();   // S6: all waves' stores drained (vmcnt0 at barrier)
        if (tid == 0) astrlx(flags + blk*64, j + 1);
    }
}

extern "C" void kernel_launch(void* const* d_in, const int* in_sizes, int n_in,
                              void* d_out, int out_size, void* d_ws, size_t ws_size,
                              hipStream_t stream)
{
    const float* x    = (const float*)d_in[0];
    const float* We   = (const float*)d_in[1];
    const float* be   = (const float*)d_in[2];
    const float* W_ih = (const float*)d_in[3];
    const float* b_ih = (const float*)d_in[4];
    const float* W_hh = (const float*)d_in[5];
    const float* b_hh = (const float*)d_in[6];
    const float* Wc   = (const float*)d_in[7];
    const float* bc   = (const float*)d_in[8];
    char* wsb = (char*)d_ws;
    float* Wx     = (float*)(wsb + OFF_WX);
    _Float16* WtP = (_Float16*)(wsb + OFF_WTP);
    _Float16* WcP = (_Float16*)(wsb + OFF_WCP);
    float* biasG  = (float*)(wsb + OFF_BIASG);
    _Float16* xH  = (_Float16*)(wsb + OFF_XH);
    int* flags    = (int*)(wsb + OFF_FLAGS);
    float* out    = (float*)d_out;

    k_build_wx<<<192, 256, 0, stream>>>(W_ih, We, Wx);
    k_prep_wtp<<<640, 512, 0, stream>>>(Wx, W_hh, WtP);
    k_prep_wcp<<<64, 512, 0, stream>>>(Wc, WcP);
    k_prep_bias<<<4, 256, 0, stream>>>(b_ih, b_hh, W_ih, be, biasG);
    k_prep_x<<<1024, 256, 0, stream>>>(x, xH);
    hipMemsetAsync(flags, 0, 64*64*sizeof(int), stream);
    k_grid<<<64, 512, 0, stream>>>(wsb, bc, out);
}

// Round 12
// 519.004 us; speedup vs baseline: 1.5014x; 1.5014x over previous
//
#include <hip/hip_runtime.h>

typedef _Float16 half8 __attribute__((ext_vector_type(8)));
typedef float f32x4 __attribute__((ext_vector_type(4)));
typedef unsigned long long ull;

// ---- ws layout (byte offsets) ----
#define OFF_WTP   0u          // WtP fp16 gate frags [16 slots][30 frags][512] = 491520
#define OFF_WCP   491520u     // WcP fp16 compress frags [8 w][8 f][512] = 65536
#define OFF_BIASG 557056u     // biasG f32 [1024] = 4096
#define OFF_WX    561152u     // Wx f32 [768][64] = 196608
#define OFF_XH    757760u     // xH fp16 [1024][64][64] = 8388608
#define OFF_HCL   9146368u    // hcL fp16 [8 xcd][2 par][2 s][32 j][8192] = 16MB (L2-local slices)
#define OFF_HCM   25923584u   // hcM fp16 [2 par][2 s][32 j][8192] = 2MB (MALL fallback)
#define OFF_FLAGS 28020736u   // flags[64] x 64-int pad
#define OFF_XCT   28037120u   // xcdtab[64] x 64-int pad
// total ~28.05 MB

// ---- coherent helpers: relaxed agent-scope (sc1 -> MALL) ----
__device__ __forceinline__ int ldrlx(const int* p) {
    return __hip_atomic_load(p, __ATOMIC_RELAXED, __HIP_MEMORY_SCOPE_AGENT);
}
__device__ __forceinline__ void astrlx(int* p, int v) {
    __hip_atomic_store(p, v, __ATOMIC_RELAXED, __HIP_MEMORY_SCOPE_AGENT);
}
__device__ __forceinline__ ull ald64(const void* p) {
    return __hip_atomic_load((const ull*)p, __ATOMIC_RELAXED, __HIP_MEMORY_SCOPE_AGENT);
}
__device__ __forceinline__ void ast64(void* p, ull v) {
    __hip_atomic_store((ull*)p, v, __ATOMIC_RELAXED, __HIP_MEMORY_SCOPE_AGENT);
}
union U128 { ull u[2]; half8 h; uint4 q; };

// ---------------- prep kernels (r10-proven) ----------------
__global__ __launch_bounds__(256) void k_build_wx(
    const float* __restrict__ W_ih, const float* __restrict__ We,
    float* __restrict__ Wx)
{
    __shared__ float WeS[128][64];
    const int tid = threadIdx.x;
    #pragma unroll
    for (int q = 0; q < 8; ++q) {
        int p = q*256 + tid;
        int e = p >> 4, k4 = p & 15;
        *(float4*)&WeS[e][k4*4] = *(const float4*)&We[e*64 + k4*4];
    }
    __syncthreads();
    int idx = blockIdx.x*256 + tid;     // 49152 -> 192 blocks
    int r = idx >> 6, k = idx & 63;
    float acc = 0.f;
    #pragma unroll 4
    for (int e = 0; e < 128; ++e) acc = fmaf(W_ih[r*128 + e], WeS[e][k], acc);
    Wx[idx] = acc;
}

__global__ __launch_bounds__(512) void k_prep_wtp(
    const float* __restrict__ Wx, const float* __restrict__ W_hh,
    _Float16* __restrict__ WtP)
{
    int bid = blockIdx.x;               // 480 = 16 slots * 30 frags
    int sw = bid / 30, f = bid % 30;
    int s = sw >> 3, w = sw & 7;
    int t = threadIdx.x;
    int l = t >> 3, e = t & 7;
    int g, ks;
    if (f < 10)      { g = 0; ks = f; }
    else if (f < 20) { g = 1; ks = f - 10; }
    else if (f < 22) { g = 2; ks = f - 20; }
    else             { g = 3; ks = f - 20; }
    int c = s*128 + w*16 + (l & 15);
    int k = ks*32 + (l >> 4)*8 + e;
    float v;
    if (k < 64) v = Wx[(g*256 + c)*64 + k];
    else {
        int rr = (g == 3) ? (512 + c) : (g*256 + c);
        v = W_hh[rr*256 + (k - 64)];
    }
    WtP[(ull)bid*512 + t] = (_Float16)v;
}

__global__ __launch_bounds__(512) void k_prep_wcp(
    const float* __restrict__ Wc, _Float16* __restrict__ WcP)
{
    int bid = blockIdx.x;               // 64
    int w = bid >> 3, f = bid & 7;
    int t = threadIdx.x;
    int l = t >> 3, e = t & 7;
    int oc = w*16 + (l & 15);
    int k = f*32 + (l >> 4)*8 + e;
    WcP[(ull)bid*512 + t] = (_Float16)Wc[oc*256 + k];
}

__global__ __launch_bounds__(256) void k_prep_bias(
    const float* __restrict__ b_ih, const float* __restrict__ b_hh,
    const float* __restrict__ W_ih, const float* __restrict__ be,
    float* __restrict__ biasG)
{
    int row = blockIdx.x*256 + threadIdx.x;   // 1024
    int g = row >> 8, c = row & 255;
    float v;
    if (g < 3) {
        int r = g*256 + c;
        float bx = b_ih[r];
        #pragma unroll 4
        for (int e = 0; e < 128; ++e) bx = fmaf(W_ih[r*128 + e], be[e], bx);
        v = (g == 0) ? bx + b_hh[c] : (g == 1) ? bx + b_hh[256 + c] : bx;
    } else v = b_hh[512 + c];
    biasG[row] = v;
}

__global__ __launch_bounds__(256) void k_prep_x(
    const float* __restrict__ x, _Float16* __restrict__ xH)
{
    int cell = blockIdx.x;              // 1024
    int i = cell >> 5, j = cell & 31;
    int b = threadIdx.x >> 2, k16 = (threadIdx.x & 3)*16;
    const float* src = &x[((b*32 + i)*32 + j)*64 + k16];
    _Float16* dst = &xH[((ull)cell*64 + b)*64 + k16];
    #pragma unroll
    for (int kk = 0; kk < 16; kk += 4) {
        float4 v = *(const float4*)&src[kk];
        dst[kk+0] = (_Float16)v.x; dst[kk+1] = (_Float16)v.y;
        dst[kk+2] = (_Float16)v.z; dst[kk+3] = (_Float16)v.w;
    }
}

// -------- persistent 2D-GRU: ch-split + partial compress (r10) with
// ADAPTIVE XCD-LOCAL L2 HANDOFF. blk swizzle puts rows 4x..4x+3 (both s)
// on one XCD slot; runtime XCC_ID handshake picks plain-L2 vs sc1-MALL
// per producer/consumer pair, so correctness never assumes the mapping.
__global__ void __launch_bounds__(512, 2)
k_grid(char* __restrict__ wsb, const float* __restrict__ bcb, float* __restrict__ out)
{
    const _Float16* WtP = (const _Float16*)(wsb + OFF_WTP);
    const _Float16* WcP = (const _Float16*)(wsb + OFF_WCP);
    const float*  biasG = (const float*)(wsb + OFF_BIASG);
    const _Float16* xH  = (const _Float16*)(wsb + OFF_XH);
    _Float16* hcL = (_Float16*)(wsb + OFF_HCL);
    _Float16* hcM = (_Float16*)(wsb + OFF_HCM);
    int* flags  = (int*)(wsb + OFF_FLAGS);
    int* xcdtab = (int*)(wsb + OFF_XCT);

    __shared__ __align__(16) _Float16 As[64][328];  // [b][k 0..319] (x|h_row|h_col)
    __shared__ __align__(16) _Float16 hnS[64][136]; // hnew own 128 ch
    __shared__ __align__(16) _Float16 hcO[64][136]; // own compress partial (persists)

    const int blk = blockIdx.x;
    const int qq = blk >> 3;
    const int s = qq & 1;
    const int i = (blk & 7)*4 + (qq >> 1);
    const int fid = i*2 + s;
    const int tid = threadIdx.x;
    const int w = tid >> 6, l = tid & 63;
    const int l15 = l & 15, lhi = l >> 4;
    const int ko = lhi*8;
    const int c = s*128 + w*16 + l15;
    const int b8 = tid >> 3, q8 = tid & 7;          // x staging (16B/thread)
    const int pb2 = tid >> 3, pc2 = (tid & 7)*16;   // plane staging (32B/thread)

    // ---- runtime XCD handshake (one-time) ----
    unsigned myxcc;
    asm volatile("s_getreg_b32 %0, hwreg(HW_REG_XCC_ID)" : "=s"(myxcc));
    myxcc &= 7;
    if (tid == 0) astrlx(xcdtab + fid*64, (int)myxcc + 1);
    int xP, xA0 = 0, xA1 = 0, xB0 = 0, xB1 = 0;
    {
        const int fP = i*2 + (1 - s);
        while ((xP = ldrlx(xcdtab + fP*64)) == 0) __builtin_amdgcn_s_sleep(1);
        if (i > 0) {
            while ((xA0 = ldrlx(xcdtab + ((i-1)*2    )*64)) == 0) __builtin_amdgcn_s_sleep(1);
            while ((xA1 = ldrlx(xcdtab + ((i-1)*2 + 1)*64)) == 0) __builtin_amdgcn_s_sleep(1);
        }
        if (i < 31) {
            while ((xB0 = ldrlx(xcdtab + ((i+1)*2    )*64)) == 0) __builtin_amdgcn_s_sleep(1);
            while ((xB1 = ldrlx(xcdtab + ((i+1)*2 + 1)*64)) == 0) __builtin_amdgcn_s_sleep(1);
        }
    }
    const int me1 = (int)myxcc + 1;
    const bool sameP  = (xP == me1);
    const bool sameA0 = (xA0 == me1), sameA1 = (xA1 == me1);
    const bool needSc1 = !sameP || (i < 31 && (xB0 != me1 || xB1 != me1));
    _Float16* hcLme = hcL + (ull)myxcc * (2u*2u*32u*8192u);

    const float bi0 = biasG[c],       bi1 = biasG[256 + c];
    const float bi2 = biasG[512 + c], bi3 = biasG[768 + c];
    const int oc = w*16 + l15;
    const float bcv = (s == 0) ? bcb[oc] : 0.f;
    half8 wcr0, wcr1, wcr2, wcr3;
    {
        const _Float16* Wcp = WcP + ((ull)(w*8 + s*4))*512 + l*8;
        wcr0 = *(const half8*)&Wcp[0];
        wcr1 = *(const half8*)&Wcp[512];
        wcr2 = *(const half8*)&Wcp[1024];
        wcr3 = *(const half8*)&Wcp[1536];
    }
    // ---- 30 gate B-frags, loaded once, pinned (live in AGPRs per r10/r11 A/B) ----
    const _Float16* Wp = WtP + ((ull)(s*8 + w)*30)*512 + (ull)l*8;
#define LW(f) (*(const half8*)&Wp[(ull)(f)*512])
    half8 b0_0=LW(0), b0_1=LW(1), b0_2=LW(2), b0_3=LW(3), b0_4=LW(4);
    half8 b0_5=LW(5), b0_6=LW(6), b0_7=LW(7), b0_8=LW(8), b0_9=LW(9);
    half8 b1_0=LW(10), b1_1=LW(11), b1_2=LW(12), b1_3=LW(13), b1_4=LW(14);
    half8 b1_5=LW(15), b1_6=LW(16), b1_7=LW(17), b1_8=LW(18), b1_9=LW(19);
    half8 b2_0=LW(20), b2_1=LW(21);
    half8 b3_2=LW(22), b3_3=LW(23), b3_4=LW(24), b3_5=LW(25);
    half8 b3_6=LW(26), b3_7=LW(27), b3_8=LW(28), b3_9=LW(29);
#undef LW
    asm volatile("" : "+v"(b0_0), "+v"(b0_1), "+v"(b0_2), "+v"(b0_3), "+v"(b0_4),
                      "+v"(b0_5), "+v"(b0_6), "+v"(b0_7), "+v"(b0_8), "+v"(b0_9));
    asm volatile("" : "+v"(b1_0), "+v"(b1_1), "+v"(b1_2), "+v"(b1_3), "+v"(b1_4),
                      "+v"(b1_5), "+v"(b1_6), "+v"(b1_7), "+v"(b1_8), "+v"(b1_9));
    asm volatile("" : "+v"(b2_0), "+v"(b2_1),
                      "+v"(b3_2), "+v"(b3_3), "+v"(b3_4), "+v"(b3_5),
                      "+v"(b3_6), "+v"(b3_7), "+v"(b3_8), "+v"(b3_9));
    asm volatile("" : "+v"(wcr0), "+v"(wcr1), "+v"(wcr2), "+v"(wcr3));

    for (int j = 0; j < 32; ++j) {
        uint4 xv = *(const uint4*)&xH[((ull)(i*32 + j)*64 + b8)*64 + q8*8];
        // ---- dependency polls (sc1 flags; all threads) ----
        if (i > 0) {
            while (ldrlx(flags + ((i-1)*2    )*64) <= j) __builtin_amdgcn_s_sleep(1);
            while (ldrlx(flags + ((i-1)*2 + 1)*64) <= j) __builtin_amdgcn_s_sleep(1);
        }
        if (j > 0)
            while (ldrlx(flags + (i*2 + 1 - s)*64) < j) __builtin_amdgcn_s_sleep(1);
        asm volatile("" ::: "memory");   // no plain-load hoisting above polls

        // ---- stage A: x | (p0+p1 row-above) | (own hcO + partner) ----
        *(uint4*)&As[b8][q8*8] = xv;
        if (i > 0) {
            const int parA = (i-1) & 1;
            half8 u0, u1, v0, v1;
            if (sameA0) {
                const _Float16* p = hcLme + ((ull)((parA*2 + 0)*32 + j))*8192 + tid*16;
                u0 = *(const half8*)p; u1 = *(const half8*)(p + 8);
            } else {
                const _Float16* p = hcM + ((ull)((parA*2 + 0)*32 + j))*8192 + tid*16;
                U128 t0; t0.u[0] = ald64(p); t0.u[1] = ald64(p + 4); u0 = t0.h;
                U128 t1; t1.u[0] = ald64(p + 8); t1.u[1] = ald64(p + 12); u1 = t1.h;
            }
            if (sameA1) {
                const _Float16* p = hcLme + ((ull)((parA*2 + 1)*32 + j))*8192 + tid*16;
                v0 = *(const half8*)p; v1 = *(const half8*)(p + 8);
            } else {
                const _Float16* p = hcM + ((ull)((parA*2 + 1)*32 + j))*8192 + tid*16;
                U128 t0; t0.u[0] = ald64(p); t0.u[1] = ald64(p + 4); v0 = t0.h;
                U128 t1; t1.u[0] = ald64(p + 8); t1.u[1] = ald64(p + 12); v1 = t1.h;
            }
            *(half8*)&As[pb2][64 + pc2]     = u0 + v0;
            *(half8*)&As[pb2][64 + pc2 + 8] = u1 + v1;
        } else {
            half8 hz = {};
            *(half8*)&As[pb2][64 + pc2]     = hz;
            *(half8*)&As[pb2][64 + pc2 + 8] = hz;
        }
        if (j > 0) {
            half8 m0, m1;
            if (sameP) {
                const _Float16* p = hcLme + ((ull)(((i&1)*2 + (1-s))*32 + (j-1)))*8192 + tid*16;
                m0 = *(const half8*)p; m1 = *(const half8*)(p + 8);
            } else {
                const _Float16* p = hcM + ((ull)(((i&1)*2 + (1-s))*32 + (j-1)))*8192 + tid*16;
                U128 t0; t0.u[0] = ald64(p); t0.u[1] = ald64(p + 4); m0 = t0.h;
                U128 t1; t1.u[0] = ald64(p + 8); t1.u[1] = ald64(p + 12); m1 = t1.h;
            }
            half8 o0 = *(const half8*)&hcO[pb2][pc2];
            half8 o1 = *(const half8*)&hcO[pb2][pc2 + 8];
            *(half8*)&As[pb2][192 + pc2]     = o0 + m0;
            *(half8*)&As[pb2][192 + pc2 + 8] = o1 + m1;
        } else {
            half8 hz = {};
            *(half8*)&As[pb2][192 + pc2]     = hz;
            *(half8*)&As[pb2][192 + pc2 + 8] = hz;
        }
        __syncthreads();   // S2: A staged

        // ---- gate GEMM: 2 m-passes, pinned register B, LDS A (r10) ----
        #pragma unroll
        for (int mp = 0; mp < 2; ++mp) {
            f32x4 g00 = {bi0,bi0,bi0,bi0}, g01 = {bi0,bi0,bi0,bi0};
            f32x4 g10 = {bi1,bi1,bi1,bi1}, g11 = {bi1,bi1,bi1,bi1};
            f32x4 g20 = {bi2,bi2,bi2,bi2}, g21 = {bi2,bi2,bi2,bi2};
            f32x4 g30 = {bi3,bi3,bi3,bi3}, g31 = {bi3,bi3,bi3,bi3};
#define GX(ks, B0, B1, B2) do { \
    half8 a0 = *(const half8*)&As[mp*32 +      l15][(ks)*32 + ko]; \
    half8 a1 = *(const half8*)&As[mp*32 + 16 + l15][(ks)*32 + ko]; \
    g00 = __builtin_amdgcn_mfma_f32_16x16x32_f16(a0, B0, g00, 0,0,0); \
    g01 = __builtin_amdgcn_mfma_f32_16x16x32_f16(a1, B0, g01, 0,0,0); \
    g10 = __builtin_amdgcn_mfma_f32_16x16x32_f16(a0, B1, g10, 0,0,0); \
    g11 = __builtin_amdgcn_mfma_f32_16x16x32_f16(a1, B1, g11, 0,0,0); \
    g20 = __builtin_amdgcn_mfma_f32_16x16x32_f16(a0, B2, g20, 0,0,0); \
    g21 = __builtin_amdgcn_mfma_f32_16x16x32_f16(a1, B2, g21, 0,0,0); } while(0)
#define GH(ks, B0, B1, B3) do { \
    half8 a0 = *(const half8*)&As[mp*32 +      l15][(ks)*32 + ko]; \
    half8 a1 = *(const half8*)&As[mp*32 + 16 + l15][(ks)*32 + ko]; \
    g00 = __builtin_amdgcn_mfma_f32_16x16x32_f16(a0, B0, g00, 0,0,0); \
    g01 = __builtin_amdgcn_mfma_f32_16x16x32_f16(a1, B0, g01, 0,0,0); \
    g10 = __builtin_amdgcn_mfma_f32_16x16x32_f16(a0, B1, g10, 0,0,0); \
    g11 = __builtin_amdgcn_mfma_f32_16x16x32_f16(a1, B1, g11, 0,0,0); \
    g30 = __builtin_amdgcn_mfma_f32_16x16x32_f16(a0, B3, g30, 0,0,0); \
    g31 = __builtin_amdgcn_mfma_f32_16x16x32_f16(a1, B3, g31, 0,0,0); } while(0)
            GX(0, b0_0, b1_0, b2_0);
            GX(1, b0_1, b1_1, b2_1);
            GH(2, b0_2, b1_2, b3_2);
            GH(3, b0_3, b1_3, b3_3);
            GH(4, b0_4, b1_4, b3_4);
            GH(5, b0_5, b1_5, b3_5);
            GH(6, b0_6, b1_6, b3_6);
            GH(7, b0_7, b1_7, b3_7);
            GH(8, b0_8, b1_8, b3_8);
            GH(9, b0_9, b1_9, b3_9);
#undef GX
#undef GH
            // nonlinearities -> hnS (separate buffer: no barrier needed here)
            #pragma unroll
            for (int r = 0; r < 4; ++r) {
                const int row0 = mp*32 + lhi*4 + r;
                float rg = 1.f/(1.f + __expf(-g00[r]));
                float zg = 1.f/(1.f + __expf(-g10[r]));
                float e2 = __expf(2.f*(g20[r] + rg*g30[r]));
                float ng = 1.f - 2.f/(e2 + 1.f);
                float hv = (float)As[row0][(s ? 192 : 64) + w*16 + l15];
                hnS[row0][w*16 + l15] = (_Float16)((1.f - zg)*ng + zg*hv);
                const int row1 = row0 + 16;
                float rg1 = 1.f/(1.f + __expf(-g01[r]));
                float zg1 = 1.f/(1.f + __expf(-g11[r]));
                float e21 = __expf(2.f*(g21[r] + rg1*g31[r]));
                float ng1 = 1.f - 2.f/(e21 + 1.f);
                float hv1 = (float)As[row1][(s ? 192 : 64) + w*16 + l15];
                hnS[row1][w*16 + l15] = (_Float16)((1.f - zg1)*ng1 + zg1*hv1);
            }
        }
        __syncthreads();   // S3: hnew complete
        // ---- compress PARTIAL (K = own 128 ch), pinned register Wc ----
        f32x4 cc0 = {bcv,bcv,bcv,bcv}, cc1 = cc0, cc2 = cc0, cc3 = cc0;
#define CSTEP(fl, WF) do { \
    half8 a0 = *(const half8*)&hnS[     l15][(fl)*32 + ko]; \
    half8 a1 = *(const half8*)&hnS[16 + l15][(fl)*32 + ko]; \
    half8 a2 = *(const half8*)&hnS[32 + l15][(fl)*32 + ko]; \
    half8 a3 = *(const half8*)&hnS[48 + l15][(fl)*32 + ko]; \
    cc0 = __builtin_amdgcn_mfma_f32_16x16x32_f16(a0, WF, cc0, 0,0,0); \
    cc1 = __builtin_amdgcn_mfma_f32_16x16x32_f16(a1, WF, cc1, 0,0,0); \
    cc2 = __builtin_amdgcn_mfma_f32_16x16x32_f16(a2, WF, cc2, 0,0,0); \
    cc3 = __builtin_amdgcn_mfma_f32_16x16x32_f16(a3, WF, cc3, 0,0,0); } while(0)
        CSTEP(0, wcr0); CSTEP(1, wcr1); CSTEP(2, wcr2); CSTEP(3, wcr3);
#undef CSTEP
        #pragma unroll
        for (int r = 0; r < 4; ++r) {
            hcO[     lhi*4 + r][oc] = (_Float16)cc0[r];
            hcO[16 + lhi*4 + r][oc] = (_Float16)cc1[r];
            hcO[32 + lhi*4 + r][oc] = (_Float16)cc2[r];
            hcO[48 + lhi*4 + r][oc] = (_Float16)cc3[r];
        }
        __syncthreads();   // S5: hcO complete
        // ---- export: plain -> my L2 slice always; sc1 -> MALL if needed ----
        {
            U128 e0, e1;
            e0.h = *(const half8*)&hcO[pb2][pc2];
            e1.h = *(const half8*)&hcO[pb2][pc2 + 8];
            _Float16* dl = hcLme + ((ull)(((i&1)*2 + s)*32 + j))*8192 + tid*16;
            *(uint4*)dl       = e0.q;
            *(uint4*)(dl + 8) = e1.q;
            if (needSc1) {
                _Float16* dm = hcM + ((ull)(((i&1)*2 + s)*32 + j))*8192 + tid*16;
                ast64(dm,      e0.u[0]); ast64(dm + 4,  e0.u[1]);
                ast64(dm + 8,  e1.u[0]); ast64(dm + 12, e1.u[1]);
            }
        }
        __syncthreads();   // S6: all waves' stores drained (vmcnt0 at barrier)
        if (tid == 0) astrlx(flags + fid*64, j + 1);
    }

    // ---- final output: WG(31,1) sums its partial with WG(31,0)'s ----
    if (i == 31 && s == 1) {
        while (ldrlx(flags + 62*64) < 32) __builtin_amdgcn_s_sleep(1);
        asm volatile("" ::: "memory");
        half8 p0, p1;
        if (sameP) {
            const _Float16* p = hcLme + ((ull)((1*2 + 0)*32 + 31))*8192 + tid*16;
            p0 = *(const half8*)p; p1 = *(const half8*)(p + 8);
        } else {
            const _Float16* p = hcM + ((ull)((1*2 + 0)*32 + 31))*8192 + tid*16;
            U128 t0; t0.u[0] = ald64(p); t0.u[1] = ald64(p + 4); p0 = t0.h;
            U128 t1; t1.u[0] = ald64(p + 8); t1.u[1] = ald64(p + 12); p1 = t1.h;
        }
        float* od = out + pb2*128 + pc2;
        #pragma unroll
        for (int e = 0; e < 8; ++e) {
            od[e]     = (float)p0[e] + (float)hcO[pb2][pc2 + e];
            od[e + 8] = (float)p1[e] + (float)hcO[pb2][pc2 + 8 + e];
        }
    }
}

extern "C" void kernel_launch(void* const* d_in, const int* in_sizes, int n_in,
                              void* d_out, int out_size, void* d_ws, size_t ws_size,
                              hipStream_t stream)
{
    const float* x    = (const float*)d_in[0];
    const float* We   = (const float*)d_in[1];
    const float* be   = (const float*)d_in[2];
    const float* W_ih = (const float*)d_in[3];
    const float* b_ih = (const float*)d_in[4];
    const float* W_hh = (const float*)d_in[5];
    const float* b_hh = (const float*)d_in[6];
    const float* Wc   = (const float*)d_in[7];
    const float* bc   = (const float*)d_in[8];
    char* wsb = (char*)d_ws;
    float* Wx     = (float*)(wsb + OFF_WX);
    _Float16* WtP = (_Float16*)(wsb + OFF_WTP);
    _Float16* WcP = (_Float16*)(wsb + OFF_WCP);
    float* biasG  = (float*)(wsb + OFF_BIASG);
    _Float16* xH  = (_Float16*)(wsb + OFF_XH);
    float* out    = (float*)d_out;

    k_build_wx<<<192, 256, 0, stream>>>(W_ih, We, Wx);
    k_prep_wtp<<<480, 512, 0, stream>>>(Wx, W_hh, WtP);
    k_prep_wcp<<<64, 512, 0, stream>>>(Wc, WcP);
    k_prep_bias<<<4, 256, 0, stream>>>(b_ih, b_hh, W_ih, be, biasG);
    k_prep_x<<<1024, 256, 0, stream>>>(x, xH);
    hipMemsetAsync(wsb + OFF_FLAGS, 0, 32768, stream);
    k_grid<<<64, 512, 0, stream>>>(wsb, bc, out);
}

// Round 14
// 518.114 us; speedup vs baseline: 1.5040x; 1.0017x over previous
//
#include <hip/hip_runtime.h>

typedef _Float16 half8 __attribute__((ext_vector_type(8)));
typedef float f32x4 __attribute__((ext_vector_type(4)));
typedef unsigned long long ull;

// ---- ws layout (byte offsets) ----
#define OFF_WTP   0u          // WtP fp16 gate frags [16 slots][30 frags][512] = 491520
#define OFF_WCP   491520u     // WcP fp16 compress frags [8 w][8 f][512] = 65536
#define OFF_BIASG 557056u     // biasG f32 [1024] = 4096
#define OFF_WX    561152u     // Wx f32 [768][64] = 196608
#define OFF_XH    757760u     // xH fp16 [1024][64][64] = 8388608
#define OFF_HCL   9146368u    // hcL fp16 [8 xcd][2 par][2 s][32 j][8192] = 16MB (L2-local)
#define OFF_HCM   25923584u   // hcM fp16 [2 par][2 s][32 j][8192] = 2MB (MALL fallback)
#define OFF_FLAGS 28020736u   // MALL flags[64] x 64-int pad = 16384
#define OFF_XCT   28037120u   // xcdtab[64] x 64-int pad = 16384
#define OFF_FLGL  28053504u   // local flags [8 xcd][64 fid][16 ints] = 32768
// memset range: OFF_FLAGS .. +65536

// ---- coherent helpers ----
__device__ __forceinline__ int ldrlx(const int* p) {
    return __hip_atomic_load(p, __ATOMIC_RELAXED, __HIP_MEMORY_SCOPE_AGENT);
}
__device__ __forceinline__ void astrlx(int* p, int v) {
    __hip_atomic_store(p, v, __ATOMIC_RELAXED, __HIP_MEMORY_SCOPE_AGENT);
}
__device__ __forceinline__ ull ald64(const void* p) {
    return __hip_atomic_load((const ull*)p, __ATOMIC_RELAXED, __HIP_MEMORY_SCOPE_AGENT);
}
__device__ __forceinline__ void ast64(void* p, ull v) {
    __hip_atomic_store((ull*)p, v, __ATOMIC_RELAXED, __HIP_MEMORY_SCOPE_AGENT);
}
// L1-bypass L2 ops (same-XCD flag fast path; always paired with MALL fallback)
__device__ __forceinline__ int ldsc0(const int* p) {
    int v;
    asm volatile("global_load_dword %0, %1, off sc0\n\ts_waitcnt vmcnt(0)"
                 : "=v"(v) : "v"(p) : "memory");
    return v;
}
__device__ __forceinline__ void stsc0(int* p, int v) {
    asm volatile("global_store_dword %0, %1, off sc0" :: "v"(p), "v"(v) : "memory");
}
union U128 { ull u[2]; half8 h; uint4 q; };

// ---------------- prep kernels (r10-proven) ----------------
__global__ __launch_bounds__(256) void k_build_wx(
    const float* __restrict__ W_ih, const float* __restrict__ We,
    float* __restrict__ Wx)
{
    __shared__ float WeS[128][64];
    const int tid = threadIdx.x;
    #pragma unroll
    for (int q = 0; q < 8; ++q) {
        int p = q*256 + tid;
        int e = p >> 4, k4 = p & 15;
        *(float4*)&WeS[e][k4*4] = *(const float4*)&We[e*64 + k4*4];
    }
    __syncthreads();
    int idx = blockIdx.x*256 + tid;     // 49152 -> 192 blocks
    int r = idx >> 6, k = idx & 63;
    float acc = 0.f;
    #pragma unroll 4
    for (int e = 0; e < 128; ++e) acc = fmaf(W_ih[r*128 + e], WeS[e][k], acc);
    Wx[idx] = acc;
}

__global__ __launch_bounds__(512) void k_prep_wtp(
    const float* __restrict__ Wx, const float* __restrict__ W_hh,
    _Float16* __restrict__ WtP)
{
    int bid = blockIdx.x;               // 480 = 16 slots * 30 frags
    int sw = bid / 30, f = bid % 30;
    int s = sw >> 3, w = sw & 7;
    int t = threadIdx.x;
    int l = t >> 3, e = t & 7;
    int g, ks;
    if (f < 10)      { g = 0; ks = f; }
    else if (f < 20) { g = 1; ks = f - 10; }
    else if (f < 22) { g = 2; ks = f - 20; }
    else             { g = 3; ks = f - 20; }
    int c = s*128 + w*16 + (l & 15);
    int k = ks*32 + (l >> 4)*8 + e;
    float v;
    if (k < 64) v = Wx[(g*256 + c)*64 + k];
    else {
        int rr = (g == 3) ? (512 + c) : (g*256 + c);
        v = W_hh[rr*256 + (k - 64)];
    }
    WtP[(ull)bid*512 + t] = (_Float16)v;
}

__global__ __launch_bounds__(512) void k_prep_wcp(
    const float* __restrict__ Wc, _Float16* __restrict__ WcP)
{
    int bid = blockIdx.x;               // 64
    int w = bid >> 3, f = bid & 7;
    int t = threadIdx.x;
    int l = t >> 3, e = t & 7;
    int oc = w*16 + (l & 15);
    int k = f*32 + (l >> 4)*8 + e;
    WcP[(ull)bid*512 + t] = (_Float16)Wc[oc*256 + k];
}

__global__ __launch_bounds__(256) void k_prep_bias(
    const float* __restrict__ b_ih, const float* __restrict__ b_hh,
    const float* __restrict__ W_ih, const float* __restrict__ be,
    float* __restrict__ biasG)
{
    int row = blockIdx.x*256 + threadIdx.x;   // 1024
    int g = row >> 8, c = row & 255;
    float v;
    if (g < 3) {
        int r = g*256 + c;
        float bx = b_ih[r];
        #pragma unroll 4
        for (int e = 0; e < 128; ++e) bx = fmaf(W_ih[r*128 + e], be[e], bx);
        v = (g == 0) ? bx + b_hh[c] : (g == 1) ? bx + b_hh[256 + c] : bx;
    } else v = b_hh[512 + c];
    biasG[row] = v;
}

__global__ __launch_bounds__(256) void k_prep_x(
    const float* __restrict__ x, _Float16* __restrict__ xH)
{
    int cell = blockIdx.x;              // 1024
    int i = cell >> 5, j = cell & 31;
    int b = threadIdx.x >> 2, k16 = (threadIdx.x & 3)*16;
    const float* src = &x[((b*32 + i)*32 + j)*64 + k16];
    _Float16* dst = &xH[((ull)cell*64 + b)*64 + k16];
    #pragma unroll
    for (int kk = 0; kk < 16; kk += 4) {
        float4 v = *(const float4*)&src[kk];
        dst[kk+0] = (_Float16)v.x; dst[kk+1] = (_Float16)v.y;
        dst[kk+2] = (_Float16)v.z; dst[kk+3] = (_Float16)v.w;
    }
}

// -------- persistent 2D-GRU: ch-split + partial compress, XCD-local L2
// handoff for data; flags = sc0-local fast path + sc1-MALL guaranteed
// fallback (dual-poll: deadlock impossible).
__global__ void __launch_bounds__(512, 2)
k_grid(char* __restrict__ wsb, const float* __restrict__ bcb, float* __restrict__ out)
{
    const _Float16* WtP = (const _Float16*)(wsb + OFF_WTP);
    const _Float16* WcP = (const _Float16*)(wsb + OFF_WCP);
    const float*  biasG = (const float*)(wsb + OFF_BIASG);
    const _Float16* xH  = (const _Float16*)(wsb + OFF_XH);
    _Float16* hcL = (_Float16*)(wsb + OFF_HCL);
    _Float16* hcM = (_Float16*)(wsb + OFF_HCM);
    int* flagsM = (int*)(wsb + OFF_FLAGS);
    int* xcdtab = (int*)(wsb + OFF_XCT);
    int* flagsL = (int*)(wsb + OFF_FLGL);

    __shared__ __align__(16) _Float16 As[64][328];
    __shared__ __align__(16) _Float16 hnS[64][136];
    __shared__ __align__(16) _Float16 hcO[64][136];

    const int blk = blockIdx.x;
    const int qq = blk >> 3;
    const int s = qq & 1;
    const int i = (blk & 7)*4 + (qq >> 1);
    const int fid = i*2 + s;
    const int tid = threadIdx.x;
    const int w = tid >> 6, l = tid & 63;
    const int l15 = l & 15, lhi = l >> 4;
    const int ko = lhi*8;
    const int c = s*128 + w*16 + l15;
    const int b8 = tid >> 3, q8 = tid & 7;
    const int pb2 = tid >> 3, pc2 = (tid & 7)*16;

    // ---- runtime XCD handshake (one-time) ----
    unsigned myxcc;
    asm volatile("s_getreg_b32 %0, hwreg(HW_REG_XCC_ID)" : "=s"(myxcc));
    myxcc &= 7;
    if (tid == 0) astrlx(xcdtab + fid*64, (int)myxcc + 1);
    int xP, xA0 = 0, xA1 = 0, xB0 = 0, xB1 = 0;
    {
        const int fP = i*2 + (1 - s);
        while ((xP = ldrlx(xcdtab + fP*64)) == 0) __builtin_amdgcn_s_sleep(1);
        if (i > 0) {
            while ((xA0 = ldrlx(xcdtab + ((i-1)*2    )*64)) == 0) __builtin_amdgcn_s_sleep(1);
            while ((xA1 = ldrlx(xcdtab + ((i-1)*2 + 1)*64)) == 0) __builtin_amdgcn_s_sleep(1);
        }
        if (i < 31) {
            while ((xB0 = ldrlx(xcdtab + ((i+1)*2    )*64)) == 0) __builtin_amdgcn_s_sleep(1);
            while ((xB1 = ldrlx(xcdtab + ((i+1)*2 + 1)*64)) == 0) __builtin_amdgcn_s_sleep(1);
        }
    }
    const int me1 = (int)myxcc + 1;
    const bool sameP  = (xP == me1);
    const bool sameA0 = (xA0 == me1), sameA1 = (xA1 == me1);
    const bool needSc1 = !sameP || (i < 31 && (xB0 != me1 || xB1 != me1));
    _Float16* hcLme = hcL + (ull)myxcc * (2u*2u*32u*8192u);
    // flag addresses: local slice valid only when producer is same-XCD
    int* lfMe  = flagsL + ((int)myxcc*64 + fid)*16;
    const int* lfP  = flagsL + ((int)myxcc*64 + (i*2 + 1 - s))*16;
    const int* lfA0 = flagsL + ((int)myxcc*64 + (((i>0?i:1)-1)*2    ))*16;
    const int* lfA1 = flagsL + ((int)myxcc*64 + (((i>0?i:1)-1)*2 + 1))*16;
    const int* mfP  = flagsM + (i*2 + 1 - s)*64;
    const int* mfA0 = flagsM + (((i>0?i:1)-1)*2    )*64;
    const int* mfA1 = flagsM + (((i>0?i:1)-1)*2 + 1)*64;

    const float bi0 = biasG[c],       bi1 = biasG[256 + c];
    const float bi2 = biasG[512 + c], bi3 = biasG[768 + c];
    const int oc = w*16 + l15;
    const float bcv = (s == 0) ? bcb[oc] : 0.f;
    half8 wcr0, wcr1, wcr2, wcr3;
    {
        const _Float16* Wcp = WcP + ((ull)(w*8 + s*4))*512 + l*8;
        wcr0 = *(const half8*)&Wcp[0];
        wcr1 = *(const half8*)&Wcp[512];
        wcr2 = *(const half8*)&Wcp[1024];
        wcr3 = *(const half8*)&Wcp[1536];
    }
    const _Float16* Wp = WtP + ((ull)(s*8 + w)*30)*512 + (ull)l*8;
#define LW(f) (*(const half8*)&Wp[(ull)(f)*512])
    half8 b0_0=LW(0), b0_1=LW(1), b0_2=LW(2), b0_3=LW(3), b0_4=LW(4);
    half8 b0_5=LW(5), b0_6=LW(6), b0_7=LW(7), b0_8=LW(8), b0_9=LW(9);
    half8 b1_0=LW(10), b1_1=LW(11), b1_2=LW(12), b1_3=LW(13), b1_4=LW(14);
    half8 b1_5=LW(15), b1_6=LW(16), b1_7=LW(17), b1_8=LW(18), b1_9=LW(19);
    half8 b2_0=LW(20), b2_1=LW(21);
    half8 b3_2=LW(22), b3_3=LW(23), b3_4=LW(24), b3_5=LW(25);
    half8 b3_6=LW(26), b3_7=LW(27), b3_8=LW(28), b3_9=LW(29);
#undef LW
    asm volatile("" : "+v"(b0_0), "+v"(b0_1), "+v"(b0_2), "+v"(b0_3), "+v"(b0_4),
                      "+v"(b0_5), "+v"(b0_6), "+v"(b0_7), "+v"(b0_8), "+v"(b0_9));
    asm volatile("" : "+v"(b1_0), "+v"(b1_1), "+v"(b1_2), "+v"(b1_3), "+v"(b1_4),
                      "+v"(b1_5), "+v"(b1_6), "+v"(b1_7), "+v"(b1_8), "+v"(b1_9));
    asm volatile("" : "+v"(b2_0), "+v"(b2_1),
                      "+v"(b3_2), "+v"(b3_3), "+v"(b3_4), "+v"(b3_5),
                      "+v"(b3_6), "+v"(b3_7), "+v"(b3_8), "+v"(b3_9));
    asm volatile("" : "+v"(wcr0), "+v"(wcr1), "+v"(wcr2), "+v"(wcr3));

    for (int j = 0; j < 32; ++j) {
        uint4 xv = *(const uint4*)&xH[((ull)(i*32 + j)*64 + b8)*64 + q8*8];
        // ---- dependency polls: sc0-local fast path, sc1-MALL fallback ----
        if (i > 0) {
            if (sameA0) { while (ldsc0(lfA0) <= j && ldrlx(mfA0) <= j) __builtin_amdgcn_s_sleep(1); }
            else        { while (ldrlx(mfA0) <= j) __builtin_amdgcn_s_sleep(1); }
            if (sameA1) { while (ldsc0(lfA1) <= j && ldrlx(mfA1) <= j) __builtin_amdgcn_s_sleep(1); }
            else        { while (ldrlx(mfA1) <= j) __builtin_amdgcn_s_sleep(1); }
        }
        if (j > 0) {
            if (sameP) { while (ldsc0(lfP) < j && ldrlx(mfP) < j) __builtin_amdgcn_s_sleep(1); }
            else       { while (ldrlx(mfP) < j) __builtin_amdgcn_s_sleep(1); }
        }
        asm volatile("" ::: "memory");

        // ---- stage A: x | (p0+p1 row-above) | (own hcO + partner) ----
        *(uint4*)&As[b8][q8*8] = xv;
        if (i > 0) {
            const int parA = (i-1) & 1;
            half8 u0, u1, v0, v1;
            if (sameA0) {
                const _Float16* p = hcLme + ((ull)((parA*2 + 0)*32 + j))*8192 + tid*16;
                u0 = *(const half8*)p; u1 = *(const half8*)(p + 8);
            } else {
                const _Float16* p = hcM + ((ull)((parA*2 + 0)*32 + j))*8192 + tid*16;
                U128 t0; t0.u[0] = ald64(p); t0.u[1] = ald64(p + 4); u0 = t0.h;
                U128 t1; t1.u[0] = ald64(p + 8); t1.u[1] = ald64(p + 12); u1 = t1.h;
            }
            if (sameA1) {
                const _Float16* p = hcLme + ((ull)((parA*2 + 1)*32 + j))*8192 + tid*16;
                v0 = *(const half8*)p; v1 = *(const half8*)(p + 8);
            } else {
                const _Float16* p = hcM + ((ull)((parA*2 + 1)*32 + j))*8192 + tid*16;
                U128 t0; t0.u[0] = ald64(p); t0.u[1] = ald64(p + 4); v0 = t0.h;
                U128 t1; t1.u[0] = ald64(p + 8); t1.u[1] = ald64(p + 12); v1 = t1.h;
            }
            *(half8*)&As[pb2][64 + pc2]     = u0 + v0;
            *(half8*)&As[pb2][64 + pc2 + 8] = u1 + v1;
        } else {
            half8 hz = {};
            *(half8*)&As[pb2][64 + pc2]     = hz;
            *(half8*)&As[pb2][64 + pc2 + 8] = hz;
        }
        if (j > 0) {
            half8 m0, m1;
            if (sameP) {
                const _Float16* p = hcLme + ((ull)(((i&1)*2 + (1-s))*32 + (j-1)))*8192 + tid*16;
                m0 = *(const half8*)p; m1 = *(const half8*)(p + 8);
            } else {
                const _Float16* p = hcM + ((ull)(((i&1)*2 + (1-s))*32 + (j-1)))*8192 + tid*16;
                U128 t0; t0.u[0] = ald64(p); t0.u[1] = ald64(p + 4); m0 = t0.h;
                U128 t1; t1.u[0] = ald64(p + 8); t1.u[1] = ald64(p + 12); m1 = t1.h;
            }
            half8 o0 = *(const half8*)&hcO[pb2][pc2];
            half8 o1 = *(const half8*)&hcO[pb2][pc2 + 8];
            *(half8*)&As[pb2][192 + pc2]     = o0 + m0;
            *(half8*)&As[pb2][192 + pc2 + 8] = o1 + m1;
        } else {
            half8 hz = {};
            *(half8*)&As[pb2][192 + pc2]     = hz;
            *(half8*)&As[pb2][192 + pc2 + 8] = hz;
        }
        __syncthreads();   // S2: A staged

        // ---- gate GEMM: 2 m-passes, pinned register B, LDS A ----
        #pragma unroll
        for (int mp = 0; mp < 2; ++mp) {
            f32x4 g00 = {bi0,bi0,bi0,bi0}, g01 = {bi0,bi0,bi0,bi0};
            f32x4 g10 = {bi1,bi1,bi1,bi1}, g11 = {bi1,bi1,bi1,bi1};
            f32x4 g20 = {bi2,bi2,bi2,bi2}, g21 = {bi2,bi2,bi2,bi2};
            f32x4 g30 = {bi3,bi3,bi3,bi3}, g31 = {bi3,bi3,bi3,bi3};
#define GX(ks, B0, B1, B2) do { \
    half8 a0 = *(const half8*)&As[mp*32 +      l15][(ks)*32 + ko]; \
    half8 a1 = *(const half8*)&As[mp*32 + 16 + l15][(ks)*32 + ko]; \
    g00 = __builtin_amdgcn_mfma_f32_16x16x32_f16(a0, B0, g00, 0,0,0); \
    g01 = __builtin_amdgcn_mfma_f32_16x16x32_f16(a1, B0, g01, 0,0,0); \
    g10 = __builtin_amdgcn_mfma_f32_16x16x32_f16(a0, B1, g10, 0,0,0); \
    g11 = __builtin_amdgcn_mfma_f32_16x16x32_f16(a1, B1, g11, 0,0,0); \
    g20 = __builtin_amdgcn_mfma_f32_16x16x32_f16(a0, B2, g20, 0,0,0); \
    g21 = __builtin_amdgcn_mfma_f32_16x16x32_f16(a1, B2, g21, 0,0,0); } while(0)
#define GH(ks, B0, B1, B3) do { \
    half8 a0 = *(const half8*)&As[mp*32 +      l15][(ks)*32 + ko]; \
    half8 a1 = *(const half8*)&As[mp*32 + 16 + l15][(ks)*32 + ko]; \
    g00 = __builtin_amdgcn_mfma_f32_16x16x32_f16(a0, B0, g00, 0,0,0); \
    g01 = __builtin_amdgcn_mfma_f32_16x16x32_f16(a1, B0, g01, 0,0,0); \
    g10 = __builtin_amdgcn_mfma_f32_16x16x32_f16(a0, B1, g10, 0,0,0); \
    g11 = __builtin_amdgcn_mfma_f32_16x16x32_f16(a1, B1, g11, 0,0,0); \
    g30 = __builtin_amdgcn_mfma_f32_16x16x32_f16(a0, B3, g30, 0,0,0); \
    g31 = __builtin_amdgcn_mfma_f32_16x16x32_f16(a1, B3, g31, 0,0,0); } while(0)
            GX(0, b0_0, b1_0, b2_0);
            GX(1, b0_1, b1_1, b2_1);
            GH(2, b0_2, b1_2, b3_2);
            GH(3, b0_3, b1_3, b3_3);
            GH(4, b0_4, b1_4, b3_4);
            GH(5, b0_5, b1_5, b3_5);
            GH(6, b0_6, b1_6, b3_6);
            GH(7, b0_7, b1_7, b3_7);
            GH(8, b0_8, b1_8, b3_8);
            GH(9, b0_9, b1_9, b3_9);
#undef GX
#undef GH
            #pragma unroll
            for (int r = 0; r < 4; ++r) {
                const int row0 = mp*32 + lhi*4 + r;
                float rg = 1.f/(1.f + __expf(-g00[r]));
                float zg = 1.f/(1.f + __expf(-g10[r]));
                float e2 = __expf(2.f*(g20[r] + rg*g30[r]));
                float ng = 1.f - 2.f/(e2 + 1.f);
                float hv = (float)As[row0][(s ? 192 : 64) + w*16 + l15];
                hnS[row0][w*16 + l15] = (_Float16)((1.f - zg)*ng + zg*hv);
                const int row1 = row0 + 16;
                float rg1 = 1.f/(1.f + __expf(-g01[r]));
                float zg1 = 1.f/(1.f + __expf(-g11[r]));
                float e21 = __expf(2.f*(g21[r] + rg1*g31[r]));
                float ng1 = 1.f - 2.f/(e21 + 1.f);
                float hv1 = (float)As[row1][(s ? 192 : 64) + w*16 + l15];
                hnS[row1][w*16 + l15] = (_Float16)((1.f - zg1)*ng1 + zg1*hv1);
            }
        }
        __syncthreads();   // S3: hnew complete
        // ---- compress PARTIAL (K = own 128 ch), pinned register Wc ----
        f32x4 cc0 = {bcv,bcv,bcv,bcv}, cc1 = cc0, cc2 = cc0, cc3 = cc0;
#define CSTEP(fl, WF) do { \
    half8 a0 = *(const half8*)&hnS[     l15][(fl)*32 + ko]; \
    half8 a1 = *(const half8*)&hnS[16 + l15][(fl)*32 + ko]; \
    half8 a2 = *(const half8*)&hnS[32 + l15][(fl)*32 + ko]; \
    half8 a3 = *(const half8*)&hnS[48 + l15][(fl)*32 + ko]; \
    cc0 = __builtin_amdgcn_mfma_f32_16x16x32_f16(a0, WF, cc0, 0,0,0); \
    cc1 = __builtin_amdgcn_mfma_f32_16x16x32_f16(a1, WF, cc1, 0,0,0); \
    cc2 = __builtin_amdgcn_mfma_f32_16x16x32_f16(a2, WF, cc2, 0,0,0); \
    cc3 = __builtin_amdgcn_mfma_f32_16x16x32_f16(a3, WF, cc3, 0,0,0); } while(0)
        CSTEP(0, wcr0); CSTEP(1, wcr1); CSTEP(2, wcr2); CSTEP(3, wcr3);
#undef CSTEP
        #pragma unroll
        for (int r = 0; r < 4; ++r) {
            hcO[     lhi*4 + r][oc] = (_Float16)cc0[r];
            hcO[16 + lhi*4 + r][oc] = (_Float16)cc1[r];
            hcO[32 + lhi*4 + r][oc] = (_Float16)cc2[r];
            hcO[48 + lhi*4 + r][oc] = (_Float16)cc3[r];
        }
        __syncthreads();   // S5: hcO complete
        // ---- export: plain -> my L2 slice always; sc1 -> MALL if needed ----
        {
            U128 e0, e1;
            e0.h = *(const half8*)&hcO[pb2][pc2];
            e1.h = *(const half8*)&hcO[pb2][pc2 + 8];
            _Float16* dl = hcLme + ((ull)(((i&1)*2 + s)*32 + j))*8192 + tid*16;
            *(uint4*)dl       = e0.q;
            *(uint4*)(dl + 8) = e1.q;
            if (needSc1) {
                _Float16* dm = hcM + ((ull)(((i&1)*2 + s)*32 + j))*8192 + tid*16;
                ast64(dm,      e0.u[0]); ast64(dm + 4,  e0.u[1]);
                ast64(dm + 8,  e1.u[0]); ast64(dm + 12, e1.u[1]);
            }
        }
        __syncthreads();   // S6: all waves' stores drained (vmcnt0 at barrier)
        if (tid == 0) {
            stsc0(lfMe, j + 1);                    // sc0 -> local L2 (fast path)
            astrlx(flagsM + fid*64, j + 1);        // sc1 -> MALL (guaranteed)
        }
    }

    // ---- final output: WG(31,1) sums its partial with WG(31,0)'s ----
    if (i == 31 && s == 1) {
        if (sameP) { while (ldsc0(lfP) < 32 && ldrlx(mfP) < 32) __builtin_amdgcn_s_sleep(1); }
        else       { while (ldrlx(mfP) < 32) __builtin_amdgcn_s_sleep(1); }
        asm volatile("" ::: "memory");
        half8 p0, p1;
        if (sameP) {
            const _Float16* p = hcLme + ((ull)((1*2 + 0)*32 + 31))*8192 + tid*16;
            p0 = *(const half8*)p; p1 = *(const half8*)(p + 8);
        } else {
            const _Float16* p = hcM + ((ull)((1*2 + 0)*32 + 31))*8192 + tid*16;
            U128 t0; t0.u[0] = ald64(p); t0.u[1] = ald64(p + 4); p0 = t0.h;
            U128 t1; t1.u[0] = ald64(p + 8); t1.u[1] = ald64(p + 12); p1 = t1.h;
        }
        float* od = out + pb2*128 + pc2;
        #pragma unroll
        for (int e = 0; e < 8; ++e) {
            od[e]     = (float)p0[e] + (float)hcO[pb2][pc2 + e];
            od[e + 8] = (float)p1[e] + (float)hcO[pb2][pc2 + 8 + e];
        }
    }
}

extern "C" void kernel_launch(void* const* d_in, const int* in_sizes, int n_in,
                              void* d_out, int out_size, void* d_ws, size_t ws_size,
                              hipStream_t stream)
{
    const float* x    = (const float*)d_in[0];
    const float* We   = (const float*)d_in[1];
    const float* be   = (const float*)d_in[2];
    const float* W_ih = (const float*)d_in[3];
    const float* b_ih = (const float*)d_in[4];
    const float* W_hh = (const float*)d_in[5];
    const float* b_hh = (const float*)d_in[6];
    const float* Wc   = (const float*)d_in[7];
    const float* bc   = (const float*)d_in[8];
    char* wsb = (char*)d_ws;
    float* Wx     = (float*)(wsb + OFF_WX);
    _Float16* WtP = (_Float16*)(wsb + OFF_WTP);
    _Float16* WcP = (_Float16*)(wsb + OFF_WCP);
    float* biasG  = (float*)(wsb + OFF_BIASG);
    _Float16* xH  = (_Float16*)(wsb + OFF_XH);
    float* out    = (float*)d_out;

    k_build_wx<<<192, 256, 0, stream>>>(W_ih, We, Wx);
    k_prep_wtp<<<480, 512, 0, stream>>>(Wx, W_hh, WtP);
    k_prep_wcp<<<64, 512, 0, stream>>>(Wc, WcP);
    k_prep_bias<<<4, 256, 0, stream>>>(b_ih, b_hh, W_ih, be, biasG);
    k_prep_x<<<1024, 256, 0, stream>>>(x, xH);
    hipMemsetAsync(wsb + OFF_FLAGS, 0, 65536, stream);
    k_grid<<<64, 512, 0, stream>>>(wsb, bc, out);
}

// Round 15
// 324.836 us; speedup vs baseline: 2.3988x; 1.5950x over previous
//
#include <hip/hip_runtime.h>

typedef _Float16 half8 __attribute__((ext_vector_type(8)));
typedef float f32x4 __attribute__((ext_vector_type(4)));
typedef unsigned long long ull;

// ---- ws layout (byte offsets) ----
#define OFF_WTP   0u          // WtP fp16 gate frags [16 slots][30 frags][512] = 491520
#define OFF_WCP   491520u     // WcP fp16 compress frags [8 w][8 f][512] = 65536
#define OFF_BIASG 557056u     // biasG f32 [1024] = 4096
#define OFF_WX    561152u     // Wx f32 [768][64] = 196608
#define OFF_XH    757760u     // xH fp16 [1024][64][64] = 8388608
#define OFF_HCL   9146368u    // hcL fp16 [8 xcd][2 par][2 h][2 s][32 j][4096] = 16MB
#define OFF_HCM   25923584u   // hcM fp16 [2 par][2 h][2 s][32 j][4096] = 2MB (MALL fallback)
#define OFF_FLAGS 28020736u   // MALL flags[128] x 64-int = 32768
#define OFF_XCT   28053504u   // xcdtab[128] x 64-int = 32768
#define OFF_FLGL  28086272u   // local flags [8 xcd][128 fid][16 ints] = 65536
// memset range: OFF_FLAGS .. +131072

// ---- coherent helpers ----
__device__ __forceinline__ int ldrlx(const int* p) {
    return __hip_atomic_load(p, __ATOMIC_RELAXED, __HIP_MEMORY_SCOPE_AGENT);
}
__device__ __forceinline__ void astrlx(int* p, int v) {
    __hip_atomic_store(p, v, __ATOMIC_RELAXED, __HIP_MEMORY_SCOPE_AGENT);
}
__device__ __forceinline__ ull ald64(const void* p) {
    return __hip_atomic_load((const ull*)p, __ATOMIC_RELAXED, __HIP_MEMORY_SCOPE_AGENT);
}
__device__ __forceinline__ void ast64(void* p, ull v) {
    __hip_atomic_store((ull*)p, v, __ATOMIC_RELAXED, __HIP_MEMORY_SCOPE_AGENT);
}
// L1-bypass L2 ops (same-XCD flag fast path; always paired with MALL fallback)
__device__ __forceinline__ int ldsc0(const int* p) {
    int v;
    asm volatile("global_load_dword %0, %1, off sc0\n\ts_waitcnt vmcnt(0)"
                 : "=v"(v) : "v"(p) : "memory");
    return v;
}
__device__ __forceinline__ void stsc0(int* p, int v) {
    asm volatile("global_store_dword %0, %1, off sc0" :: "v"(p), "v"(v) : "memory");
}
union U128 { ull u[2]; half8 h; uint4 q; };

// ---------------- prep kernels (r10-proven) ----------------
__global__ __launch_bounds__(256) void k_build_wx(
    const float* __restrict__ W_ih, const float* __restrict__ We,
    float* __restrict__ Wx)
{
    __shared__ float WeS[128][64];
    const int tid = threadIdx.x;
    #pragma unroll
    for (int q = 0; q < 8; ++q) {
        int p = q*256 + tid;
        int e = p >> 4, k4 = p & 15;
        *(float4*)&WeS[e][k4*4] = *(const float4*)&We[e*64 + k4*4];
    }
    __syncthreads();
    int idx = blockIdx.x*256 + tid;     // 49152 -> 192 blocks
    int r = idx >> 6, k = idx & 63;
    float acc = 0.f;
    #pragma unroll 4
    for (int e = 0; e < 128; ++e) acc = fmaf(W_ih[r*128 + e], WeS[e][k], acc);
    Wx[idx] = acc;
}

__global__ __launch_bounds__(512) void k_prep_wtp(
    const float* __restrict__ Wx, const float* __restrict__ W_hh,
    _Float16* __restrict__ WtP)
{
    int bid = blockIdx.x;               // 480 = 16 slots * 30 frags
    int sw = bid / 30, f = bid % 30;
    int s = sw >> 3, w = sw & 7;
    int t = threadIdx.x;
    int l = t >> 3, e = t & 7;
    int g, ks;
    if (f < 10)      { g = 0; ks = f; }
    else if (f < 20) { g = 1; ks = f - 10; }
    else if (f < 22) { g = 2; ks = f - 20; }
    else             { g = 3; ks = f - 20; }
    int c = s*128 + w*16 + (l & 15);
    int k = ks*32 + (l >> 4)*8 + e;
    float v;
    if (k < 64) v = Wx[(g*256 + c)*64 + k];
    else {
        int rr = (g == 3) ? (512 + c) : (g*256 + c);
        v = W_hh[rr*256 + (k - 64)];
    }
    WtP[(ull)bid*512 + t] = (_Float16)v;
}

__global__ __launch_bounds__(512) void k_prep_wcp(
    const float* __restrict__ Wc, _Float16* __restrict__ WcP)
{
    int bid = blockIdx.x;               // 64
    int w = bid >> 3, f = bid & 7;
    int t = threadIdx.x;
    int l = t >> 3, e = t & 7;
    int oc = w*16 + (l & 15);
    int k = f*32 + (l >> 4)*8 + e;
    WcP[(ull)bid*512 + t] = (_Float16)Wc[oc*256 + k];
}

__global__ __launch_bounds__(256) void k_prep_bias(
    const float* __restrict__ b_ih, const float* __restrict__ b_hh,
    const float* __restrict__ W_ih, const float* __restrict__ be,
    float* __restrict__ biasG)
{
    int row = blockIdx.x*256 + threadIdx.x;   // 1024
    int g = row >> 8, c = row & 255;
    float v;
    if (g < 3) {
        int r = g*256 + c;
        float bx = b_ih[r];
        #pragma unroll 4
        for (int e = 0; e < 128; ++e) bx = fmaf(W_ih[r*128 + e], be[e], bx);
        v = (g == 0) ? bx + b_hh[c] : (g == 1) ? bx + b_hh[256 + c] : bx;
    } else v = b_hh[512 + c];
    biasG[row] = v;
}

__global__ __launch_bounds__(256) void k_prep_x(
    const float* __restrict__ x, _Float16* __restrict__ xH)
{
    int cell = blockIdx.x;              // 1024
    int i = cell >> 5, j = cell & 31;
    int b = threadIdx.x >> 2, k16 = (threadIdx.x & 3)*16;
    const float* src = &x[((b*32 + i)*32 + j)*64 + k16];
    _Float16* dst = &xH[((ull)cell*64 + b)*64 + k16];
    #pragma unroll
    for (int kk = 0; kk < 16; kk += 4) {
        float4 v = *(const float4*)&src[kk];
        dst[kk+0] = (_Float16)v.x; dst[kk+1] = (_Float16)v.y;
        dst[kk+2] = (_Float16)v.z; dst[kk+3] = (_Float16)v.w;
    }
}

// -------- persistent 2D-GRU: 4 WGs/row = batch-split x ch-split, partial
// compress, XCD-local L2 handoff, dual flags. 128 WGs x 512 thr.
// WG (i, h, s): row i, batches h*32..+31, state channels s*128..+127.
// hcL plane index P(par,h,s,j) = (((par*2+h)*2+s)*32+j)*4096 halfs (8KB).
__global__ void __launch_bounds__(512, 2)
k_grid(char* __restrict__ wsb, const float* __restrict__ bcb, float* __restrict__ out)
{
    const _Float16* WtP = (const _Float16*)(wsb + OFF_WTP);
    const _Float16* WcP = (const _Float16*)(wsb + OFF_WCP);
    const float*  biasG = (const float*)(wsb + OFF_BIASG);
    const _Float16* xH  = (const _Float16*)(wsb + OFF_XH);
    _Float16* hcL = (_Float16*)(wsb + OFF_HCL);
    _Float16* hcM = (_Float16*)(wsb + OFF_HCM);
    int* flagsM = (int*)(wsb + OFF_FLAGS);
    int* xcdtab = (int*)(wsb + OFF_XCT);
    int* flagsL = (int*)(wsb + OFF_FLGL);

    __shared__ __align__(16) _Float16 As[32][328];   // [b][k 0..319] x|h_row|h_col
    __shared__ __align__(16) _Float16 hnS[32][136];  // hnew own 128 ch
    __shared__ __align__(16) _Float16 hcO[32][136];  // own compress partial (persists)

    const int blk = blockIdx.x;
    const int qq = blk >> 3;
    const int s = qq & 1;
    const int h = (qq >> 1) & 1;
    const int i = (blk & 7)*4 + (qq >> 2);
    const int fid = i*4 + h*2 + s;
    const int tid = threadIdx.x;
    const int w = tid >> 6, l = tid & 63;
    const int l15 = l & 15, lhi = l >> 4;
    const int ko = lhi*8;
    const int cl = w*16 + l15;                       // channel local to s-half
    const int c  = s*128 + cl;                       // global state channel
    const int b16 = tid >> 4, q16 = tid & 15;        // 32 rows x 16 cols staging

    // ---- runtime XCD handshake (one-time) ----
    unsigned myxcc;
    asm volatile("s_getreg_b32 %0, hwreg(HW_REG_XCC_ID)" : "=s"(myxcc));
    myxcc &= 7;
    if (tid == 0) astrlx(xcdtab + fid*64, (int)myxcc + 1);
    int xP, xA0 = 0, xA1 = 0, xB0 = 0, xB1 = 0;
    {
        const int fP = i*4 + h*2 + (1 - s);
        while ((xP = ldrlx(xcdtab + fP*64)) == 0) __builtin_amdgcn_s_sleep(1);
        if (i > 0) {
            while ((xA0 = ldrlx(xcdtab + ((i-1)*4 + h*2    )*64)) == 0) __builtin_amdgcn_s_sleep(1);
            while ((xA1 = ldrlx(xcdtab + ((i-1)*4 + h*2 + 1)*64)) == 0) __builtin_amdgcn_s_sleep(1);
        }
        if (i < 31) {
            while ((xB0 = ldrlx(xcdtab + ((i+1)*4 + h*2    )*64)) == 0) __builtin_amdgcn_s_sleep(1);
            while ((xB1 = ldrlx(xcdtab + ((i+1)*4 + h*2 + 1)*64)) == 0) __builtin_amdgcn_s_sleep(1);
        }
    }
    const int me1 = (int)myxcc + 1;
    const bool sameP  = (xP == me1);
    const bool sameA0 = (xA0 == me1), sameA1 = (xA1 == me1);
    const bool needSc1 = !sameP || (i < 31 && (xB0 != me1 || xB1 != me1));
    _Float16* hcLme = hcL + (ull)myxcc * (2u*2u*2u*32u*4096u);
    int* lfMe  = flagsL + ((int)myxcc*128 + fid)*16;
    const int* lfP  = flagsL + ((int)myxcc*128 + (i*4 + h*2 + 1 - s))*16;
    const int* lfA0 = flagsL + ((int)myxcc*128 + (((i>0?i:1)-1)*4 + h*2    ))*16;
    const int* lfA1 = flagsL + ((int)myxcc*128 + (((i>0?i:1)-1)*4 + h*2 + 1))*16;
    const int* mfP  = flagsM + (i*4 + h*2 + 1 - s)*64;
    const int* mfA0 = flagsM + ((((i>0?i:1)-1)*4 + h*2    ))*64;
    const int* mfA1 = flagsM + ((((i>0?i:1)-1)*4 + h*2 + 1))*64;

    const float bi0 = biasG[c],       bi1 = biasG[256 + c];
    const float bi2 = biasG[512 + c], bi3 = biasG[768 + c];
    const int oc = cl;                                // compress out col (local)
    const float bcv = (s == 0) ? bcb[oc] : 0.f;
    half8 wcr0, wcr1, wcr2, wcr3;
    {
        const _Float16* Wcp = WcP + ((ull)(w*8 + s*4))*512 + l*8;
        wcr0 = *(const half8*)&Wcp[0];
        wcr1 = *(const half8*)&Wcp[512];
        wcr2 = *(const half8*)&Wcp[1024];
        wcr3 = *(const half8*)&Wcp[1536];
    }
    const _Float16* Wp = WtP + ((ull)(s*8 + w)*30)*512 + (ull)l*8;
#define LW(f) (*(const half8*)&Wp[(ull)(f)*512])
    half8 b0_0=LW(0), b0_1=LW(1), b0_2=LW(2), b0_3=LW(3), b0_4=LW(4);
    half8 b0_5=LW(5), b0_6=LW(6), b0_7=LW(7), b0_8=LW(8), b0_9=LW(9);
    half8 b1_0=LW(10), b1_1=LW(11), b1_2=LW(12), b1_3=LW(13), b1_4=LW(14);
    half8 b1_5=LW(15), b1_6=LW(16), b1_7=LW(17), b1_8=LW(18), b1_9=LW(19);
    half8 b2_0=LW(20), b2_1=LW(21);
    half8 b3_2=LW(22), b3_3=LW(23), b3_4=LW(24), b3_5=LW(25);
    half8 b3_6=LW(26), b3_7=LW(27), b3_8=LW(28), b3_9=LW(29);
#undef LW
    asm volatile("" : "+v"(b0_0), "+v"(b0_1), "+v"(b0_2), "+v"(b0_3), "+v"(b0_4),
                      "+v"(b0_5), "+v"(b0_6), "+v"(b0_7), "+v"(b0_8), "+v"(b0_9));
    asm volatile("" : "+v"(b1_0), "+v"(b1_1), "+v"(b1_2), "+v"(b1_3), "+v"(b1_4),
                      "+v"(b1_5), "+v"(b1_6), "+v"(b1_7), "+v"(b1_8), "+v"(b1_9));
    asm volatile("" : "+v"(b2_0), "+v"(b2_1),
                      "+v"(b3_2), "+v"(b3_3), "+v"(b3_4), "+v"(b3_5),
                      "+v"(b3_6), "+v"(b3_7), "+v"(b3_8), "+v"(b3_9));
    asm volatile("" : "+v"(wcr0), "+v"(wcr1), "+v"(wcr2), "+v"(wcr3));

#define PLANE(par, hh, ss, jj) ((ull)((((par)*2 + (hh))*2 + (ss))*32 + (jj)) * 4096u)

    for (int j = 0; j < 32; ++j) {
        uint2 xv = *(const uint2*)&xH[((ull)(i*32 + j)*64 + (h*32 + b16))*64 + q16*4];
        // ---- dependency polls: sc0-local fast path + sc1-MALL fallback ----
        if (i > 0) {
            if (sameA0) { while (ldsc0(lfA0) <= j && ldrlx(mfA0) <= j) __builtin_amdgcn_s_sleep(1); }
            else        { while (ldrlx(mfA0) <= j) __builtin_amdgcn_s_sleep(1); }
            if (sameA1) { while (ldsc0(lfA1) <= j && ldrlx(mfA1) <= j) __builtin_amdgcn_s_sleep(1); }
            else        { while (ldrlx(mfA1) <= j) __builtin_amdgcn_s_sleep(1); }
        }
        if (j > 0) {
            if (sameP) { while (ldsc0(lfP) < j && ldrlx(mfP) < j) __builtin_amdgcn_s_sleep(1); }
            else       { while (ldrlx(mfP) < j) __builtin_amdgcn_s_sleep(1); }
        }
        asm volatile("" ::: "memory");

        // ---- stage A: x | (p0+p1 row-above, own h) | (own hcO + partner) ----
        *(uint2*)&As[b16][q16*4] = xv;
        if (i > 0) {
            const int parA = (i-1) & 1;
            half8 u0, v0;
            if (sameA0) {
                u0 = *(const half8*)(hcLme + PLANE(parA, h, 0, j) + tid*8);
            } else {
                const _Float16* p = hcM + PLANE(parA, h, 0, j) + tid*8;
                U128 t0; t0.u[0] = ald64(p); t0.u[1] = ald64(p + 4); u0 = t0.h;
            }
            if (sameA1) {
                v0 = *(const half8*)(hcLme + PLANE(parA, h, 1, j) + tid*8);
            } else {
                const _Float16* p = hcM + PLANE(parA, h, 1, j) + tid*8;
                U128 t0; t0.u[0] = ald64(p); t0.u[1] = ald64(p + 4); v0 = t0.h;
            }
            *(half8*)&As[b16][64 + q16*8] = u0 + v0;
        } else {
            half8 hz = {};
            *(half8*)&As[b16][64 + q16*8] = hz;
        }
        if (j > 0) {
            half8 m0;
            if (sameP) {
                m0 = *(const half8*)(hcLme + PLANE((i&1), h, (1-s), (j-1)) + tid*8);
            } else {
                const _Float16* p = hcM + PLANE((i&1), h, (1-s), (j-1)) + tid*8;
                U128 t0; t0.u[0] = ald64(p); t0.u[1] = ald64(p + 4); m0 = t0.h;
            }
            half8 o0 = *(const half8*)&hcO[b16][q16*8];
            *(half8*)&As[b16][192 + q16*8] = o0 + m0;
        } else {
            half8 hz = {};
            *(half8*)&As[b16][192 + q16*8] = hz;
        }
        __syncthreads();   // S2: A staged

        // ---- gate GEMM: single pass, M=32 (2 A-tiles), pinned register B ----
        f32x4 g00 = {bi0,bi0,bi0,bi0}, g01 = {bi0,bi0,bi0,bi0};
        f32x4 g10 = {bi1,bi1,bi1,bi1}, g11 = {bi1,bi1,bi1,bi1};
        f32x4 g20 = {bi2,bi2,bi2,bi2}, g21 = {bi2,bi2,bi2,bi2};
        f32x4 g30 = {bi3,bi3,bi3,bi3}, g31 = {bi3,bi3,bi3,bi3};
#define GX(ks, B0, B1, B2) do { \
    half8 a0 = *(const half8*)&As[     l15][(ks)*32 + ko]; \
    half8 a1 = *(const half8*)&As[16 + l15][(ks)*32 + ko]; \
    g00 = __builtin_amdgcn_mfma_f32_16x16x32_f16(a0, B0, g00, 0,0,0); \
    g01 = __builtin_amdgcn_mfma_f32_16x16x32_f16(a1, B0, g01, 0,0,0); \
    g10 = __builtin_amdgcn_mfma_f32_16x16x32_f16(a0, B1, g10, 0,0,0); \
    g11 = __builtin_amdgcn_mfma_f32_16x16x32_f16(a1, B1, g11, 0,0,0); \
    g20 = __builtin_amdgcn_mfma_f32_16x16x32_f16(a0, B2, g20, 0,0,0); \
    g21 = __builtin_amdgcn_mfma_f32_16x16x32_f16(a1, B2, g21, 0,0,0); } while(0)
#define GH(ks, B0, B1, B3) do { \
    half8 a0 = *(const half8*)&As[     l15][(ks)*32 + ko]; \
    half8 a1 = *(const half8*)&As[16 + l15][(ks)*32 + ko]; \
    g00 = __builtin_amdgcn_mfma_f32_16x16x32_f16(a0, B0, g00, 0,0,0); \
    g01 = __builtin_amdgcn_mfma_f32_16x16x32_f16(a1, B0, g01, 0,0,0); \
    g10 = __builtin_amdgcn_mfma_f32_16x16x32_f16(a0, B1, g10, 0,0,0); \
    g11 = __builtin_amdgcn_mfma_f32_16x16x32_f16(a1, B1, g11, 0,0,0); \
    g30 = __builtin_amdgcn_mfma_f32_16x16x32_f16(a0, B3, g30, 0,0,0); \
    g31 = __builtin_amdgcn_mfma_f32_16x16x32_f16(a1, B3, g31, 0,0,0); } while(0)
        GX(0, b0_0, b1_0, b2_0);
        GX(1, b0_1, b1_1, b2_1);
        GH(2, b0_2, b1_2, b3_2);
        GH(3, b0_3, b1_3, b3_3);
        GH(4, b0_4, b1_4, b3_4);
        GH(5, b0_5, b1_5, b3_5);
        GH(6, b0_6, b1_6, b3_6);
        GH(7, b0_7, b1_7, b3_7);
        GH(8, b0_8, b1_8, b3_8);
        GH(9, b0_9, b1_9, b3_9);
#undef GX
#undef GH
        // ---- nonlinearities -> hnS (blend hval from staged A) ----
        #pragma unroll
        for (int r = 0; r < 4; ++r) {
            const int row0 = lhi*4 + r;
            float rg = 1.f/(1.f + __expf(-g00[r]));
            float zg = 1.f/(1.f + __expf(-g10[r]));
            float e2 = __expf(2.f*(g20[r] + rg*g30[r]));
            float ng = 1.f - 2.f/(e2 + 1.f);
            float hv = (float)As[row0][(s ? 192 : 64) + cl];
            hnS[row0][cl] = (_Float16)((1.f - zg)*ng + zg*hv);
            const int row1 = row0 + 16;
            float rg1 = 1.f/(1.f + __expf(-g01[r]));
            float zg1 = 1.f/(1.f + __expf(-g11[r]));
            float e21 = __expf(2.f*(g21[r] + rg1*g31[r]));
            float ng1 = 1.f - 2.f/(e21 + 1.f);
            float hv1 = (float)As[row1][(s ? 192 : 64) + cl];
            hnS[row1][cl] = (_Float16)((1.f - zg1)*ng1 + zg1*hv1);
        }
        __syncthreads();   // S3: hnew complete
        // ---- compress PARTIAL (K = own 128 ch), pinned register Wc ----
        f32x4 cc0 = {bcv,bcv,bcv,bcv}, cc1 = cc0;
#define CSTEP(fl, WF) do { \
    half8 a0 = *(const half8*)&hnS[     l15][(fl)*32 + ko]; \
    half8 a1 = *(const half8*)&hnS[16 + l15][(fl)*32 + ko]; \
    cc0 = __builtin_amdgcn_mfma_f32_16x16x32_f16(a0, WF, cc0, 0,0,0); \
    cc1 = __builtin_amdgcn_mfma_f32_16x16x32_f16(a1, WF, cc1, 0,0,0); } while(0)
        CSTEP(0, wcr0); CSTEP(1, wcr1); CSTEP(2, wcr2); CSTEP(3, wcr3);
#undef CSTEP
        #pragma unroll
        for (int r = 0; r < 4; ++r) {
            hcO[     lhi*4 + r][oc] = (_Float16)cc0[r];
            hcO[16 + lhi*4 + r][oc] = (_Float16)cc1[r];
        }
        __syncthreads();   // S5: hcO complete
        // ---- export: plain -> my L2 slice always; sc1 -> MALL if needed ----
        {
            U128 e0;
            e0.h = *(const half8*)&hcO[b16][q16*8];
            _Float16* dl = hcLme + PLANE((i&1), h, s, j) + tid*8;
            *(uint4*)dl = e0.q;
            if (needSc1) {
                _Float16* dm = hcM + PLANE((i&1), h, s, j) + tid*8;
                ast64(dm,     e0.u[0]);
                ast64(dm + 4, e0.u[1]);
            }
        }
        __syncthreads();   // S6: all waves' stores drained (vmcnt0 at barrier)
        if (tid == 0) {
            stsc0(lfMe, j + 1);                    // sc0 -> local L2 (fast path)
            astrlx(flagsM + fid*64, j + 1);        // sc1 -> MALL (guaranteed)
        }
    }

    // ---- final output: WG(31,h,1) sums its partial with WG(31,h,0)'s ----
    if (i == 31 && s == 1) {
        if (sameP) { while (ldsc0(lfP) < 32 && ldrlx(mfP) < 32) __builtin_amdgcn_s_sleep(1); }
        else       { while (ldrlx(mfP) < 32) __builtin_amdgcn_s_sleep(1); }
        asm volatile("" ::: "memory");
        half8 p0;
        if (sameP) {
            p0 = *(const half8*)(hcLme + PLANE(1, h, 0, 31) + tid*8);
        } else {
            const _Float16* p = hcM + PLANE(1, h, 0, 31) + tid*8;
            U128 t0; t0.u[0] = ald64(p); t0.u[1] = ald64(p + 4); p0 = t0.h;
        }
        float* od = out + (h*32 + b16)*128 + q16*8;
        #pragma unroll
        for (int e = 0; e < 8; ++e)
            od[e] = (float)p0[e] + (float)hcO[b16][q16*8 + e];
    }
#undef PLANE
}

extern "C" void kernel_launch(void* const* d_in, const int* in_sizes, int n_in,
                              void* d_out, int out_size, void* d_ws, size_t ws_size,
                              hipStream_t stream)
{
    const float* x    = (const float*)d_in[0];
    const float* We   = (const float*)d_in[1];
    const float* be   = (const float*)d_in[2];
    const float* W_ih = (const float*)d_in[3];
    const float* b_ih = (const float*)d_in[4];
    const float* W_hh = (const float*)d_in[5];
    const float* b_hh = (const float*)d_in[6];
    const float* Wc   = (const float*)d_in[7];
    const float* bc   = (const float*)d_in[8];
    char* wsb = (char*)d_ws;
    float* Wx     = (float*)(wsb + OFF_WX);
    _Float16* WtP = (_Float16*)(wsb + OFF_WTP);
    _Float16* WcP = (_Float16*)(wsb + OFF_WCP);
    float* biasG  = (float*)(wsb + OFF_BIASG);
    _Float16* xH  = (_Float16*)(wsb + OFF_XH);
    float* out    = (float*)d_out;

    k_build_wx<<<192, 256, 0, stream>>>(W_ih, We, Wx);
    k_prep_wtp<<<480, 512, 0, stream>>>(Wx, W_hh, WtP);
    k_prep_wcp<<<64, 512, 0, stream>>>(Wc, WcP);
    k_prep_bias<<<4, 256, 0, stream>>>(b_ih, b_hh, W_ih, be, biasG);
    k_prep_x<<<1024, 256, 0, stream>>>(x, xH);
    hipMemsetAsync(wsb + OFF_FLAGS, 0, 131072, stream);
    k_grid<<<128, 512, 0, stream>>>(wsb, bc, out);
}